// Round 7
// baseline (359.933 us; speedup 1.0000x reference)
//
#include <hip/hip_runtime.h>
#include <math.h>

typedef float f32x2 __attribute__((ext_vector_type(2)));

__device__ __forceinline__ float gelu_f(float x) {
    return 0.5f * x * (1.0f + erff(x * 0.7071067811865476f));
}

// ---------------------------------------------------------------------------
// L1: conv1 (blocks 0..2047)  UNION  prep (blocks 2048..2049)
// conv1: x[128,1,128,128] -> h1[128,16,64,64]  (conv+pool+gelu, R6 code)
// prep: ccp[k]=||cb_k||^2 ; w3t (transformed conv3 weights, in d_out scratch);
//       w4t; w2d (conv2 weights duplicated as {w,w} f32x2, in d_out scratch)
// ---------------------------------------------------------------------------
__global__ __launch_bounds__(256) void kA(const float* __restrict__ x,
                                          const float* __restrict__ w1,
                                          const float* __restrict__ b1,
                                          float* __restrict__ h1,
                                          const float* __restrict__ cb,
                                          const float* __restrict__ w3,
                                          const float* __restrict__ w4,
                                          float* __restrict__ ccp,
                                          float* __restrict__ w3t,
                                          float* __restrict__ w4t,
                                          f32x2* __restrict__ w2d,
                                          const float* __restrict__ w2) {
    const int blk = blockIdx.x;
    const int t = threadIdx.x;
    if (blk >= 2048) {
        const int id = (blk - 2048) * 256 + t;   // 0..511
        {
            const float* row = cb + id * 32;
            float s = 0.f;
#pragma unroll
            for (int c = 0; c < 32; ++c) s += row[c] * row[c];
            ccp[id] = s;
        }
        {
            const float* w = w3 + id * 9;   // id = co*32+ci
            const float T00 = w[0], T01 = w[1], T02 = w[2];
            const float T10 = w[3] + w[6], T11 = w[4] + w[7], T12 = w[5] + w[8];
            const float T20 = w[0] + w[3], T21 = w[1] + w[4], T22 = w[2] + w[5];
            const float T30 = w[6], T31 = w[7], T32 = w[8];
            float* o = w3t + id * 16;
            o[0] = T00; o[1] = T00 + T01; o[2] = T01 + T02; o[3] = T02;
            o[4] = T10; o[5] = T10 + T11; o[6] = T11 + T12; o[7] = T12;
            o[8] = T20; o[9] = T20 + T21; o[10] = T21 + T22; o[11] = T22;
            o[12] = T30; o[13] = T30 + T31; o[14] = T31 + T32; o[15] = T32;
        }
        if (id < 16) {
            const float* w = w4 + id * 9;
            const float T00 = w[0], T01 = w[1], T02 = w[2];
            const float T10 = w[3] + w[6], T11 = w[4] + w[7], T12 = w[5] + w[8];
            const float T20 = w[0] + w[3], T21 = w[1] + w[4], T22 = w[2] + w[5];
            const float T30 = w[6], T31 = w[7], T32 = w[8];
            float* o = w4t + id * 16;
            o[0] = T00; o[1] = T00 + T01; o[2] = T01 + T02; o[3] = T02;
            o[4] = T10; o[5] = T10 + T11; o[6] = T11 + T12; o[7] = T12;
            o[8] = T20; o[9] = T20 + T21; o[10] = T21 + T22; o[11] = T22;
            o[12] = T30; o[13] = T30 + T31; o[14] = T31 + T32; o[15] = T32;
        }
        for (int i = id; i < 4608; i += 512) {   // 32co*16ci*9
            const float wv = w2[i];
            w2d[i] = (f32x2){wv, wv};
        }
        return;
    }
    __shared__ float xs[34 * 38];
    const int b = blk >> 4;
    const int tile = blk & 15;
    const int ti = (tile >> 2) << 4, tj = (tile & 3) << 4;
    const float* xb = x + b * 16384;
    for (int i = t; i < 34 * 34; i += 256) {
        const int r = i / 34, c = i % 34;
        const int gr = 2 * ti - 1 + r, gc = 2 * tj - 1 + c;
        const float v = ((unsigned)gr < 128u && (unsigned)gc < 128u) ? xb[gr * 128 + gc] : 0.f;
        xs[r * 38 + (c & 1) * 19 + (c >> 1)] = v;
    }
    __syncthreads();
    const int jj = t & 15, ii = t >> 4;
    float pat[4][4];
#pragma unroll
    for (int r = 0; r < 4; r++) {
        const int row = (2 * ii + r) * 38;
        pat[r][0] = xs[row + jj];
        pat[r][1] = xs[row + 19 + jj];
        pat[r][2] = xs[row + jj + 1];
        pat[r][3] = xs[row + 20 + jj];
    }
    const int obase = b * 65536 + (ti + ii) * 64 + (tj + jj);
#pragma unroll 2
    for (int co = 0; co < 16; co++) {
        const float* wr = w1 + co * 9;
        float w[9];
#pragma unroll
        for (int k = 0; k < 9; k++) w[k] = wr[k];
        float s00 = 0.f, s01 = 0.f, s10 = 0.f, s11 = 0.f;
#pragma unroll
        for (int ty = 0; ty < 3; ty++)
#pragma unroll
            for (int tx = 0; tx < 3; tx++) {
                const float wv = w[ty * 3 + tx];
                s00 += wv * pat[ty][tx];
                s01 += wv * pat[ty][tx + 1];
                s10 += wv * pat[ty + 1][tx];
                s11 += wv * pat[ty + 1][tx + 1];
            }
        const float m = fmaxf(fmaxf(s00, s01), fmaxf(s10, s11)) + b1[co];
        h1[obase + co * 4096] = gelu_f(m);
    }
}

// ---------------------------------------------------------------------------
// L2: conv2 (16->32, 3x3, SAME) + maxpool2 — f32x2 packed; weights from the
// duplicated-pair table w2d ({w,w} -> direct 64-bit uniform operand).
// Math order identical to R6 -> bit-identical h.
// ---------------------------------------------------------------------------
__global__ __launch_bounds__(256) void k_conv2(const float* __restrict__ h1,
                                               const f32x2* __restrict__ w2d,
                                               const float* __restrict__ b2,
                                               float* __restrict__ h) {
    __shared__ float hs[16 * 360];
    const int blk = blockIdx.x;
    const int b = blk >> 4;
    const int tile = blk & 15;
    const int ti = (tile >> 2) << 3, tj = (tile & 3) << 3;
    const int t = threadIdx.x;
    const float* h1b = h1 + b * 65536;
    for (int i = t; i < 16 * 324; i += 256) {
        const int ci = i / 324, rc = i % 324, r = rc / 18, c = rc % 18;
        const int gr = 2 * ti - 1 + r, gc = 2 * tj - 1 + c;
        const float v = ((unsigned)gr < 64u && (unsigned)gc < 64u) ? h1b[ci * 4096 + gr * 64 + gc] : 0.f;
        hs[ci * 360 + r * 20 + (c & 1) * 10 + (c >> 1)] = v;
    }
    __syncthreads();
    const int co0 = __builtin_amdgcn_readfirstlane((t >> 6) << 3);
    const int lane = t & 63;
    const int irow = lane >> 3, j = lane & 7;
    f32x2 A[8], B[8];
#pragma unroll
    for (int q = 0; q < 8; q++) { A[q] = (f32x2){0.f, 0.f}; B[q] = (f32x2){0.f, 0.f}; }
    const f32x2* wbase = w2d + co0 * 144;
#pragma unroll 4
    for (int ci = 0; ci < 16; ci++) {
        f32x2 P[4][3];
#pragma unroll
        for (int r = 0; r < 4; r++) {
            const int row = ci * 360 + (2 * irow + r) * 20;
            const float e0 = hs[row + j];
            const float o0 = hs[row + 10 + j];
            const float e1 = hs[row + j + 1];
            const float o1 = hs[row + 11 + j];
            P[r][0] = (f32x2){e0, o0};
            P[r][1] = (f32x2){o0, e1};
            P[r][2] = (f32x2){e1, o1};
        }
#pragma unroll
        for (int q = 0; q < 8; q++) {
            const f32x2* wr = wbase + q * 144 + ci * 9;
            f32x2 W[9];
#pragma unroll
            for (int k = 0; k < 9; k++) W[k] = wr[k];
#pragma unroll
            for (int ty = 0; ty < 3; ty++)
#pragma unroll
                for (int tx = 0; tx < 3; tx++) {
                    A[q] += P[ty][tx] * W[ty * 3 + tx];
                    B[q] += P[ty + 1][tx] * W[ty * 3 + tx];
                }
        }
    }
    float* hb = h + (b * 32 + co0) * 1024 + (ti + irow) * 32 + tj + j;
#pragma unroll
    for (int q = 0; q < 8; q++) {
        hb[q * 1024] = fmaxf(fmaxf(A[q].x, A[q].y), fmaxf(B[q].x, B[q].y)) + b2[co0 + q];
    }
}

// ---------------------------------------------------------------------------
// L3: conv3 (blocks 0..511)  UNION  vq (blocks 512..2559)
// conv3: h -> g (R6 code, weights from w3t scratch)
// vq: per block 64 n; 4 waves = 4 k-ranges of 128 codes (same inner loop as
// R6 vq_part); LDS combine ascending wave order, strict < (== jnp.argmin).
// Writes idx directly + per-block loss partial. No part buffer.
// ---------------------------------------------------------------------------
__global__ __launch_bounds__(256) void kB(const float* __restrict__ h,
                                          const float* __restrict__ w3t,
                                          const float* __restrict__ b3,
                                          float* __restrict__ g,
                                          const float* __restrict__ cb,
                                          const float* __restrict__ ccp,
                                          float* __restrict__ idx_out,
                                          float* __restrict__ pa) {
    __shared__ float smem[16 * 350];
    const int blk = blockIdx.x;
    const int t = threadIdx.x;
    if (blk >= 512) {
        const int vblk = blk - 512;           // 0..2047
        const int n0 = vblk * 64;
        const int wave = t >> 6, lane = t & 63;
        const int n = n0 + lane;
        const int b = n >> 10, pos = n & 1023;
        const float* hb = h + b * 32768 + pos;
        float z[32];
        float zz = 0.f;
#pragma unroll
        for (int c = 0; c < 32; ++c) {
            z[c] = hb[c * 1024];
            zz += z[c] * z[c];
        }
        f32x2 z2[16];
#pragma unroll
        for (int i = 0; i < 16; ++i) z2[i] = (f32x2){z[2 * i], z[2 * i + 1]};
        const int kbase = wave << 7;
        const float* cbb = cb + (kbase << 5);
        const float* ccb = ccp + kbase;
        float bd = 3.4e38f;
        int bk = 0;
#pragma unroll 1
        for (int kk = 0; kk < 128; kk += 2) {
            const f32x2* r0 = (const f32x2*)(cbb + (kk << 5));
            const f32x2* r1 = (const f32x2*)(cbb + (kk << 5) + 32);
            f32x2 D0 = (f32x2){0.f, 0.f};
            f32x2 D1 = (f32x2){0.f, 0.f};
#pragma unroll
            for (int i = 0; i < 16; ++i) {
                D0 += z2[i] * r0[i];
                D1 += z2[i] * r1[i];
            }
            const float dot0 = D0.x + D0.y;
            const float dot1 = D1.x + D1.y;
            const float e0 = (zz - 2.f * dot0) + ccb[kk];
            const float e1 = (zz - 2.f * dot1) + ccb[kk + 1];
            if (e0 < bd) { bd = e0; bk = kbase + kk; }
            if (e1 < bd) { bd = e1; bk = kbase + kk + 1; }
        }
        float2* sm = (float2*)smem;           // [4][64]
        sm[wave * 64 + lane] = make_float2(bd, (float)bk);
        __syncthreads();
        if (t < 64) {
            float2 p0 = sm[t];
            float2 p1 = sm[64 + t];
            float2 p2 = sm[128 + t];
            float2 p3 = sm[192 + t];
            float fd = p0.x, fk = p0.y;
            if (p1.x < fd) { fd = p1.x; fk = p1.y; }
            if (p2.x < fd) { fd = p2.x; fk = p2.y; }
            if (p3.x < fd) { fd = p3.x; fk = p3.y; }
            idx_out[n0 + t] = fk;
            float s = fd;
#pragma unroll
            for (int m = 1; m < 64; m <<= 1) s += __shfl_xor(s, m, 64);
            if (t == 0) pa[vblk] = s;
        }
        return;
    }
    float* hS = smem;
    const int b = blk >> 2, strip = blk & 3;
    const int i0 = strip * 8;
    const int co0 = __builtin_amdgcn_readfirstlane((t >> 6) << 2);
    const int lane = t & 63;
    const int rp = lane >> 3, cg = lane & 7;
    float acc[4][2][8];
#pragma unroll
    for (int cq = 0; cq < 4; cq++)
#pragma unroll
        for (int rr = 0; rr < 2; rr++)
#pragma unroll
            for (int u = 0; u < 8; u++) acc[cq][rr][u] = 0.f;
    const float* hb = h + b * 32768;
#pragma unroll 1
    for (int chunk = 0; chunk < 2; chunk++) {
        __syncthreads();
        for (int i = t; i < 16 * 340; i += 256) {
            const int cil = i / 340, rc = i % 340, r = rc / 34, c = rc % 34;
            const int gr = i0 - 1 + r, gc = c - 1;
            const float v = ((unsigned)gr < 32u && (unsigned)gc < 32u)
                ? hb[(chunk * 16 + cil) * 1024 + gr * 32 + gc] : 0.f;
            hS[cil * 350 + r * 35 + c] = v;
        }
        __syncthreads();
#pragma unroll 2
        for (int cil = 0; cil < 16; cil++) {
            const int ci = chunk * 16 + cil;
            float colr[3][6];
#pragma unroll
            for (int rr = 0; rr < 3; rr++) {
                const int rowb = cil * 350 + (rp + rr) * 35 + 4 * cg;
#pragma unroll
                for (int u = 0; u < 6; u++) colr[rr][u] = hS[rowb + u];
            }
#pragma unroll
            for (int cq = 0; cq < 4; cq++) {
                const float* wt = w3t + ((co0 + cq) * 32 + ci) * 16;
                const float T00 = wt[0], O00 = wt[1], E01 = wt[2], T02 = wt[3];
                const float T10 = wt[4], O10 = wt[5], E11 = wt[6], T12 = wt[7];
                const float T20 = wt[8], O20 = wt[9], E21 = wt[10], T22 = wt[11];
                const float T30 = wt[12], O30 = wt[13], E31 = wt[14], T32 = wt[15];
#pragma unroll
                for (int mm = 0; mm < 4; mm++) {
                    acc[cq][0][2 * mm]     += T00 * colr[0][mm] + E01 * colr[0][mm + 1] + T10 * colr[1][mm] + E11 * colr[1][mm + 1];
                    acc[cq][0][2 * mm + 1] += O00 * colr[0][mm + 1] + T02 * colr[0][mm + 2] + O10 * colr[1][mm + 1] + T12 * colr[1][mm + 2];
                    acc[cq][1][2 * mm]     += T20 * colr[1][mm] + E21 * colr[1][mm + 1] + T30 * colr[2][mm] + E31 * colr[2][mm + 1];
                    acc[cq][1][2 * mm + 1] += O20 * colr[1][mm + 1] + T22 * colr[1][mm + 2] + O30 * colr[2][mm + 1] + T32 * colr[2][mm + 2];
                }
            }
        }
    }
    const int p_e = strip * 16 + 2 * rp;
#pragma unroll
    for (int cq = 0; cq < 4; cq++) {
        const float bias = b3[co0 + cq];
        float* gb = g + (b * 16 + co0 + cq) * 4096 + p_e * 64 + 8 * cg;
#pragma unroll
        for (int rr = 0; rr < 2; rr++) {
            float4 v0, v1;
            v0.x = gelu_f(acc[cq][rr][0] + bias);
            v0.y = gelu_f(acc[cq][rr][1] + bias);
            v0.z = gelu_f(acc[cq][rr][2] + bias);
            v0.w = gelu_f(acc[cq][rr][3] + bias);
            v1.x = gelu_f(acc[cq][rr][4] + bias);
            v1.y = gelu_f(acc[cq][rr][5] + bias);
            v1.z = gelu_f(acc[cq][rr][6] + bias);
            v1.w = gelu_f(acc[cq][rr][7] + bias);
            *(float4*)(gb + rr * 64) = v0;
            *(float4*)(gb + rr * 64 + 4) = v1;
        }
    }
}

// ---------------------------------------------------------------------------
// L4: conv4 (blocks 0..1023)  UNION  loss reduce (block 1024)
// ---------------------------------------------------------------------------
__global__ __launch_bounds__(256) void kC(const float* __restrict__ g,
                                          const float* __restrict__ w4t,
                                          const float* __restrict__ b4,
                                          float* __restrict__ out,
                                          const float* __restrict__ pa,
                                          float* __restrict__ loss) {
    __shared__ float smem[8 * 690];
    const int blk = blockIdx.x;
    const int t = threadIdx.x;
    if (blk >= 1024) {
        float s = 0.f;
        for (int i = t; i < 2048; i += 256) s += pa[i];
        smem[t] = s;
        __syncthreads();
        for (int off = 128; off > 0; off >>= 1) {
            if (t < off) smem[t] += smem[t + off];
            __syncthreads();
        }
        if (t == 0) loss[0] = smem[0] * (1.0f / 4194304.0f);
        return;
    }
    float* gS = smem;
    const int b = blk >> 3, strip = blk & 7;
    const int i0 = strip * 8;
    const int rp = t >> 5, cg = t & 31;
    float acc[2][4];
#pragma unroll
    for (int rr = 0; rr < 2; rr++)
#pragma unroll
        for (int u = 0; u < 4; u++) acc[rr][u] = 0.f;
    const float* gbs = g + b * 65536;
#pragma unroll 1
    for (int chunk = 0; chunk < 2; chunk++) {
        __syncthreads();
        for (int i = t; i < 8 * 660; i += 256) {
            const int cil = i / 660, rc = i % 660, r = rc / 66, c = rc % 66;
            const int gr = i0 - 1 + r, gc = c - 1;
            const float v = ((unsigned)gr < 64u && (unsigned)gc < 64u)
                ? gbs[(chunk * 8 + cil) * 4096 + gr * 64 + gc] : 0.f;
            gS[cil * 690 + r * 69 + c] = v;
        }
        __syncthreads();
#pragma unroll 2
        for (int cil = 0; cil < 8; cil++) {
            const int ci = chunk * 8 + cil;
            float colv[3][4];
#pragma unroll
            for (int rr = 0; rr < 3; rr++) {
                const int rowb = cil * 690 + (rp + rr) * 69 + 2 * cg;
#pragma unroll
                for (int u = 0; u < 4; u++) colv[rr][u] = gS[rowb + u];
            }
            const float* wt = w4t + ci * 16;
            const float T00 = wt[0], O00 = wt[1], E01 = wt[2], T02 = wt[3];
            const float T10 = wt[4], O10 = wt[5], E11 = wt[6], T12 = wt[7];
            const float T20 = wt[8], O20 = wt[9], E21 = wt[10], T22 = wt[11];
            const float T30 = wt[12], O30 = wt[13], E31 = wt[14], T32 = wt[15];
#pragma unroll
            for (int mm = 0; mm < 2; mm++) {
                acc[0][2 * mm]     += T00 * colv[0][mm] + E01 * colv[0][mm + 1] + T10 * colv[1][mm] + E11 * colv[1][mm + 1];
                acc[0][2 * mm + 1] += O00 * colv[0][mm + 1] + T02 * colv[0][mm + 2] + O10 * colv[1][mm + 1] + T12 * colv[1][mm + 2];
                acc[1][2 * mm]     += T20 * colv[1][mm] + E21 * colv[1][mm + 1] + T30 * colv[2][mm] + E31 * colv[2][mm + 1];
                acc[1][2 * mm + 1] += O20 * colv[1][mm + 1] + T22 * colv[1][mm + 2] + O30 * colv[2][mm + 1] + T32 * colv[2][mm + 2];
            }
        }
    }
    const float bias = b4[0];
    const int p_e = strip * 16 + 2 * rp;
    float* ob = out + b * 16384 + p_e * 128 + 4 * cg;
#pragma unroll
    for (int rr = 0; rr < 2; rr++) {
        float4 v;
        v.x = fminf(fmaxf(acc[rr][0] + bias, -1.f), 1.f);
        v.y = fminf(fmaxf(acc[rr][1] + bias, -1.f), 1.f);
        v.z = fminf(fmaxf(acc[rr][2] + bias, -1.f), 1.f);
        v.w = fminf(fmaxf(acc[rr][3] + bias, -1.f), 1.f);
        *(float4*)(ob + rr * 128) = v;
    }
}

extern "C" void kernel_launch(void* const* d_in, const int* in_sizes, int n_in,
                              void* d_out, int out_size, void* d_ws, size_t ws_size,
                              hipStream_t stream) {
    const float* x  = (const float*)d_in[0];
    const float* w1 = (const float*)d_in[1];
    const float* b1 = (const float*)d_in[2];
    const float* w2 = (const float*)d_in[3];
    const float* b2 = (const float*)d_in[4];
    const float* cb = (const float*)d_in[5];
    const float* w3 = (const float*)d_in[6];
    const float* b3 = (const float*)d_in[7];
    const float* w4 = (const float*)d_in[8];
    const float* b4 = (const float*)d_in[9];

    float* ws = (float*)d_ws;
    float* h1 = ws;                   // 8388608 floats [128,16,64,64]
    float* h  = ws + 8388608;         // 4194304 floats [128,32,32,32]
    float* g  = h1;                   // alias: h1 dead after conv2
    float* ccp = ws + 12582912;       // 512
    float* pa  = ws + 12583424;       // 2048 (per-vq-block loss partials)
    float* w4t = ws + 12585472;       // 256

    float* outp = (float*)d_out;      // final: [out 2097152][idx 131072][loss 1]
    // d_out's `out` region doubles as weight-table scratch until kC overwrites it:
    float* w3t = outp;                // 8192 floats (L1 write, L3 read)
    f32x2* w2d = (f32x2*)(outp + 8192); // 4608 f32x2 (L1 write, L2 read)
    float* idx = outp + 2097152;
    float* loss = outp + 2228224;

    kA<<<2050, 256, 0, stream>>>(x, w1, b1, h1, cb, w3, w4, ccp, w3t, w4t, w2d, w2);
    k_conv2<<<2048, 256, 0, stream>>>(h1, w2d, b2, h);
    kB<<<2560, 256, 0, stream>>>(h, w3t, b3, g, cb, ccp, idx, pa);
    kC<<<1025, 256, 0, stream>>>(g, w4t, b4, outp, pa, loss);
}

// Round 8
// 217.942 us; speedup vs baseline: 1.6515x; 1.6515x over previous
//
#include <hip/hip_runtime.h>
#include <math.h>

typedef float f32x2 __attribute__((ext_vector_type(2)));

__device__ __forceinline__ float gelu_f(float x) {
    return 0.5f * x * (1.0f + erff(x * 0.7071067811865476f));
}

// ---------------------------------------------------------------------------
// L1: conv1 (blocks 0..2047)  UNION  prep (blocks 2048..2049)
// ---------------------------------------------------------------------------
__global__ __launch_bounds__(256) void kA(const float* __restrict__ x,
                                          const float* __restrict__ w1,
                                          const float* __restrict__ b1,
                                          float* __restrict__ h1,
                                          const float* __restrict__ cb,
                                          const float* __restrict__ w3,
                                          const float* __restrict__ w4,
                                          float* __restrict__ ccp,
                                          float* __restrict__ w3t,
                                          float* __restrict__ w4t,
                                          f32x2* __restrict__ w2d,
                                          const float* __restrict__ w2) {
    const int blk = blockIdx.x;
    const int t = threadIdx.x;
    if (blk >= 2048) {
        const int id = (blk - 2048) * 256 + t;   // 0..511
        {
            const float* row = cb + id * 32;
            float s = 0.f;
#pragma unroll
            for (int c = 0; c < 32; ++c) s += row[c] * row[c];
            ccp[id] = s;
        }
        {
            const float* w = w3 + id * 9;   // id = co*32+ci
            const float T00 = w[0], T01 = w[1], T02 = w[2];
            const float T10 = w[3] + w[6], T11 = w[4] + w[7], T12 = w[5] + w[8];
            const float T20 = w[0] + w[3], T21 = w[1] + w[4], T22 = w[2] + w[5];
            const float T30 = w[6], T31 = w[7], T32 = w[8];
            float* o = w3t + id * 16;
            o[0] = T00; o[1] = T00 + T01; o[2] = T01 + T02; o[3] = T02;
            o[4] = T10; o[5] = T10 + T11; o[6] = T11 + T12; o[7] = T12;
            o[8] = T20; o[9] = T20 + T21; o[10] = T21 + T22; o[11] = T22;
            o[12] = T30; o[13] = T30 + T31; o[14] = T31 + T32; o[15] = T32;
        }
        if (id < 16) {
            const float* w = w4 + id * 9;
            const float T00 = w[0], T01 = w[1], T02 = w[2];
            const float T10 = w[3] + w[6], T11 = w[4] + w[7], T12 = w[5] + w[8];
            const float T20 = w[0] + w[3], T21 = w[1] + w[4], T22 = w[2] + w[5];
            const float T30 = w[6], T31 = w[7], T32 = w[8];
            float* o = w4t + id * 16;
            o[0] = T00; o[1] = T00 + T01; o[2] = T01 + T02; o[3] = T02;
            o[4] = T10; o[5] = T10 + T11; o[6] = T11 + T12; o[7] = T12;
            o[8] = T20; o[9] = T20 + T21; o[10] = T21 + T22; o[11] = T22;
            o[12] = T30; o[13] = T30 + T31; o[14] = T31 + T32; o[15] = T32;
        }
        for (int i = id; i < 4608; i += 512) {   // 32co*16ci*9
            const float wv = w2[i];
            w2d[i] = (f32x2){wv, wv};
        }
        return;
    }
    __shared__ float xs[34 * 38];
    const int b = blk >> 4;
    const int tile = blk & 15;
    const int ti = (tile >> 2) << 4, tj = (tile & 3) << 4;
    const float* xb = x + b * 16384;
    for (int i = t; i < 34 * 34; i += 256) {
        const int r = i / 34, c = i % 34;
        const int gr = 2 * ti - 1 + r, gc = 2 * tj - 1 + c;
        const float v = ((unsigned)gr < 128u && (unsigned)gc < 128u) ? xb[gr * 128 + gc] : 0.f;
        xs[r * 38 + (c & 1) * 19 + (c >> 1)] = v;
    }
    __syncthreads();
    const int jj = t & 15, ii = t >> 4;
    float pat[4][4];
#pragma unroll
    for (int r = 0; r < 4; r++) {
        const int row = (2 * ii + r) * 38;
        pat[r][0] = xs[row + jj];
        pat[r][1] = xs[row + 19 + jj];
        pat[r][2] = xs[row + jj + 1];
        pat[r][3] = xs[row + 20 + jj];
    }
    const int obase = b * 65536 + (ti + ii) * 64 + (tj + jj);
#pragma unroll 2
    for (int co = 0; co < 16; co++) {
        const float* wr = w1 + co * 9;
        float w[9];
#pragma unroll
        for (int k = 0; k < 9; k++) w[k] = wr[k];
        float s00 = 0.f, s01 = 0.f, s10 = 0.f, s11 = 0.f;
#pragma unroll
        for (int ty = 0; ty < 3; ty++)
#pragma unroll
            for (int tx = 0; tx < 3; tx++) {
                const float wv = w[ty * 3 + tx];
                s00 += wv * pat[ty][tx];
                s01 += wv * pat[ty][tx + 1];
                s10 += wv * pat[ty + 1][tx];
                s11 += wv * pat[ty + 1][tx + 1];
            }
        const float m = fmaxf(fmaxf(s00, s01), fmaxf(s10, s11)) + b1[co];
        h1[obase + co * 4096] = gelu_f(m);
    }
}

// ---------------------------------------------------------------------------
// L2: conv2 (16->32, 3x3, SAME) + maxpool2 — f32x2 packed, w2d pair table.
// ---------------------------------------------------------------------------
__global__ __launch_bounds__(256) void k_conv2(const float* __restrict__ h1,
                                               const f32x2* __restrict__ w2d,
                                               const float* __restrict__ b2,
                                               float* __restrict__ h) {
    __shared__ float hs[16 * 360];
    const int blk = blockIdx.x;
    const int b = blk >> 4;
    const int tile = blk & 15;
    const int ti = (tile >> 2) << 3, tj = (tile & 3) << 3;
    const int t = threadIdx.x;
    const float* h1b = h1 + b * 65536;
    for (int i = t; i < 16 * 324; i += 256) {
        const int ci = i / 324, rc = i % 324, r = rc / 18, c = rc % 18;
        const int gr = 2 * ti - 1 + r, gc = 2 * tj - 1 + c;
        const float v = ((unsigned)gr < 64u && (unsigned)gc < 64u) ? h1b[ci * 4096 + gr * 64 + gc] : 0.f;
        hs[ci * 360 + r * 20 + (c & 1) * 10 + (c >> 1)] = v;
    }
    __syncthreads();
    const int co0 = __builtin_amdgcn_readfirstlane((t >> 6) << 3);
    const int lane = t & 63;
    const int irow = lane >> 3, j = lane & 7;
    f32x2 A[8], B[8];
#pragma unroll
    for (int q = 0; q < 8; q++) { A[q] = (f32x2){0.f, 0.f}; B[q] = (f32x2){0.f, 0.f}; }
    const f32x2* wbase = w2d + co0 * 144;
#pragma unroll 4
    for (int ci = 0; ci < 16; ci++) {
        f32x2 P[4][3];
#pragma unroll
        for (int r = 0; r < 4; r++) {
            const int row = ci * 360 + (2 * irow + r) * 20;
            const float e0 = hs[row + j];
            const float o0 = hs[row + 10 + j];
            const float e1 = hs[row + j + 1];
            const float o1 = hs[row + 11 + j];
            P[r][0] = (f32x2){e0, o0};
            P[r][1] = (f32x2){o0, e1};
            P[r][2] = (f32x2){e1, o1};
        }
#pragma unroll
        for (int q = 0; q < 8; q++) {
            const f32x2* wr = wbase + q * 144 + ci * 9;
            f32x2 W[9];
#pragma unroll
            for (int k = 0; k < 9; k++) W[k] = wr[k];
#pragma unroll
            for (int ty = 0; ty < 3; ty++)
#pragma unroll
                for (int tx = 0; tx < 3; tx++) {
                    A[q] += P[ty][tx] * W[ty * 3 + tx];
                    B[q] += P[ty + 1][tx] * W[ty * 3 + tx];
                }
        }
    }
    float* hb = h + (b * 32 + co0) * 1024 + (ti + irow) * 32 + tj + j;
#pragma unroll
    for (int q = 0; q < 8; q++) {
        hb[q * 1024] = fmaxf(fmaxf(A[q].x, A[q].y), fmaxf(B[q].x, B[q].y)) + b2[co0 + q];
    }
}

// ---------------------------------------------------------------------------
// L3: conv3 (blocks 0..511)  UNION  vq (blocks 512..2559)
// FIX vs R7: wave id forced into SGPR via readfirstlane so the codebook
// address stream is wave-uniform -> s_load broadcasts (the R6 fast path).
// ---------------------------------------------------------------------------
__global__ __launch_bounds__(256) void kB(const float* __restrict__ h,
                                          const float* __restrict__ w3t,
                                          const float* __restrict__ b3,
                                          float* __restrict__ g,
                                          const float* __restrict__ cb,
                                          const float* __restrict__ ccp,
                                          float* __restrict__ idx_out,
                                          float* __restrict__ pa) {
    __shared__ float smem[16 * 350];
    const int blk = blockIdx.x;
    const int t = threadIdx.x;
    if (blk >= 512) {
        const int vblk = blk - 512;           // 0..2047
        const int n0 = vblk * 64;
        const int wave = __builtin_amdgcn_readfirstlane(t >> 6);  // SGPR wave id
        const int lane = t & 63;
        const int n = n0 + lane;
        const int b = n >> 10, pos = n & 1023;
        const float* hb = h + b * 32768 + pos;
        float z[32];
        float zz = 0.f;
#pragma unroll
        for (int c = 0; c < 32; ++c) {
            z[c] = hb[c * 1024];
            zz += z[c] * z[c];
        }
        f32x2 z2[16];
#pragma unroll
        for (int i = 0; i < 16; ++i) z2[i] = (f32x2){z[2 * i], z[2 * i + 1]};
        const int kbase = wave << 7;
        const float* cbb = cb + (kbase << 5);
        const float* ccb = ccp + kbase;
        float bd = 3.4e38f;
        int bk = 0;
#pragma unroll 1
        for (int kk = 0; kk < 128; kk += 2) {
            const f32x2* r0 = (const f32x2*)(cbb + (kk << 5));
            const f32x2* r1 = (const f32x2*)(cbb + (kk << 5) + 32);
            f32x2 D0 = (f32x2){0.f, 0.f};
            f32x2 D1 = (f32x2){0.f, 0.f};
#pragma unroll
            for (int i = 0; i < 16; ++i) {
                D0 += z2[i] * r0[i];
                D1 += z2[i] * r1[i];
            }
            const float dot0 = D0.x + D0.y;
            const float dot1 = D1.x + D1.y;
            const float e0 = (zz - 2.f * dot0) + ccb[kk];
            const float e1 = (zz - 2.f * dot1) + ccb[kk + 1];
            if (e0 < bd) { bd = e0; bk = kbase + kk; }
            if (e1 < bd) { bd = e1; bk = kbase + kk + 1; }
        }
        float2* sm = (float2*)smem;           // [4][64]
        sm[wave * 64 + lane] = make_float2(bd, (float)bk);
        __syncthreads();
        if (t < 64) {
            float2 p0 = sm[t];
            float2 p1 = sm[64 + t];
            float2 p2 = sm[128 + t];
            float2 p3 = sm[192 + t];
            float fd = p0.x, fk = p0.y;
            if (p1.x < fd) { fd = p1.x; fk = p1.y; }
            if (p2.x < fd) { fd = p2.x; fk = p2.y; }
            if (p3.x < fd) { fd = p3.x; fk = p3.y; }
            idx_out[n0 + t] = fk;
            float s = fd;
#pragma unroll
            for (int m = 1; m < 64; m <<= 1) s += __shfl_xor(s, m, 64);
            if (t == 0) pa[vblk] = s;
        }
        return;
    }
    float* hS = smem;
    const int b = blk >> 2, strip = blk & 3;
    const int i0 = strip * 8;
    const int co0 = __builtin_amdgcn_readfirstlane((t >> 6) << 2);
    const int lane = t & 63;
    const int rp = lane >> 3, cg = lane & 7;
    float acc[4][2][8];
#pragma unroll
    for (int cq = 0; cq < 4; cq++)
#pragma unroll
        for (int rr = 0; rr < 2; rr++)
#pragma unroll
            for (int u = 0; u < 8; u++) acc[cq][rr][u] = 0.f;
    const float* hb = h + b * 32768;
#pragma unroll 1
    for (int chunk = 0; chunk < 2; chunk++) {
        __syncthreads();
        for (int i = t; i < 16 * 340; i += 256) {
            const int cil = i / 340, rc = i % 340, r = rc / 34, c = rc % 34;
            const int gr = i0 - 1 + r, gc = c - 1;
            const float v = ((unsigned)gr < 32u && (unsigned)gc < 32u)
                ? hb[(chunk * 16 + cil) * 1024 + gr * 32 + gc] : 0.f;
            hS[cil * 350 + r * 35 + c] = v;
        }
        __syncthreads();
#pragma unroll 2
        for (int cil = 0; cil < 16; cil++) {
            const int ci = chunk * 16 + cil;
            float colr[3][6];
#pragma unroll
            for (int rr = 0; rr < 3; rr++) {
                const int rowb = cil * 350 + (rp + rr) * 35 + 4 * cg;
#pragma unroll
                for (int u = 0; u < 6; u++) colr[rr][u] = hS[rowb + u];
            }
#pragma unroll
            for (int cq = 0; cq < 4; cq++) {
                const float* wt = w3t + ((co0 + cq) * 32 + ci) * 16;
                const float T00 = wt[0], O00 = wt[1], E01 = wt[2], T02 = wt[3];
                const float T10 = wt[4], O10 = wt[5], E11 = wt[6], T12 = wt[7];
                const float T20 = wt[8], O20 = wt[9], E21 = wt[10], T22 = wt[11];
                const float T30 = wt[12], O30 = wt[13], E31 = wt[14], T32 = wt[15];
#pragma unroll
                for (int mm = 0; mm < 4; mm++) {
                    acc[cq][0][2 * mm]     += T00 * colr[0][mm] + E01 * colr[0][mm + 1] + T10 * colr[1][mm] + E11 * colr[1][mm + 1];
                    acc[cq][0][2 * mm + 1] += O00 * colr[0][mm + 1] + T02 * colr[0][mm + 2] + O10 * colr[1][mm + 1] + T12 * colr[1][mm + 2];
                    acc[cq][1][2 * mm]     += T20 * colr[1][mm] + E21 * colr[1][mm + 1] + T30 * colr[2][mm] + E31 * colr[2][mm + 1];
                    acc[cq][1][2 * mm + 1] += O20 * colr[1][mm + 1] + T22 * colr[1][mm + 2] + O30 * colr[2][mm + 1] + T32 * colr[2][mm + 2];
                }
            }
        }
    }
    const int p_e = strip * 16 + 2 * rp;
#pragma unroll
    for (int cq = 0; cq < 4; cq++) {
        const float bias = b3[co0 + cq];
        float* gb = g + (b * 16 + co0 + cq) * 4096 + p_e * 64 + 8 * cg;
#pragma unroll
        for (int rr = 0; rr < 2; rr++) {
            float4 v0, v1;
            v0.x = gelu_f(acc[cq][rr][0] + bias);
            v0.y = gelu_f(acc[cq][rr][1] + bias);
            v0.z = gelu_f(acc[cq][rr][2] + bias);
            v0.w = gelu_f(acc[cq][rr][3] + bias);
            v1.x = gelu_f(acc[cq][rr][4] + bias);
            v1.y = gelu_f(acc[cq][rr][5] + bias);
            v1.z = gelu_f(acc[cq][rr][6] + bias);
            v1.w = gelu_f(acc[cq][rr][7] + bias);
            *(float4*)(gb + rr * 64) = v0;
            *(float4*)(gb + rr * 64 + 4) = v1;
        }
    }
}

// ---------------------------------------------------------------------------
// L4: conv4 (blocks 0..1023)  UNION  loss reduce (block 1024)
// ---------------------------------------------------------------------------
__global__ __launch_bounds__(256) void kC(const float* __restrict__ g,
                                          const float* __restrict__ w4t,
                                          const float* __restrict__ b4,
                                          float* __restrict__ out,
                                          const float* __restrict__ pa,
                                          float* __restrict__ loss) {
    __shared__ float smem[8 * 690];
    const int blk = blockIdx.x;
    const int t = threadIdx.x;
    if (blk >= 1024) {
        float s = 0.f;
        for (int i = t; i < 2048; i += 256) s += pa[i];
        smem[t] = s;
        __syncthreads();
        for (int off = 128; off > 0; off >>= 1) {
            if (t < off) smem[t] += smem[t + off];
            __syncthreads();
        }
        if (t == 0) loss[0] = smem[0] * (1.0f / 4194304.0f);
        return;
    }
    float* gS = smem;
    const int b = blk >> 3, strip = blk & 7;
    const int i0 = strip * 8;
    const int rp = t >> 5, cg = t & 31;
    float acc[2][4];
#pragma unroll
    for (int rr = 0; rr < 2; rr++)
#pragma unroll
        for (int u = 0; u < 4; u++) acc[rr][u] = 0.f;
    const float* gbs = g + b * 65536;
#pragma unroll 1
    for (int chunk = 0; chunk < 2; chunk++) {
        __syncthreads();
        for (int i = t; i < 8 * 660; i += 256) {
            const int cil = i / 660, rc = i % 660, r = rc / 66, c = rc % 66;
            const int gr = i0 - 1 + r, gc = c - 1;
            const float v = ((unsigned)gr < 64u && (unsigned)gc < 64u)
                ? gbs[(chunk * 8 + cil) * 4096 + gr * 64 + gc] : 0.f;
            gS[cil * 690 + r * 69 + c] = v;
        }
        __syncthreads();
#pragma unroll 2
        for (int cil = 0; cil < 8; cil++) {
            const int ci = chunk * 8 + cil;
            float colv[3][4];
#pragma unroll
            for (int rr = 0; rr < 3; rr++) {
                const int rowb = cil * 690 + (rp + rr) * 69 + 2 * cg;
#pragma unroll
                for (int u = 0; u < 4; u++) colv[rr][u] = gS[rowb + u];
            }
            const float* wt = w4t + ci * 16;
            const float T00 = wt[0], O00 = wt[1], E01 = wt[2], T02 = wt[3];
            const float T10 = wt[4], O10 = wt[5], E11 = wt[6], T12 = wt[7];
            const float T20 = wt[8], O20 = wt[9], E21 = wt[10], T22 = wt[11];
            const float T30 = wt[12], O30 = wt[13], E31 = wt[14], T32 = wt[15];
#pragma unroll
            for (int mm = 0; mm < 2; mm++) {
                acc[0][2 * mm]     += T00 * colv[0][mm] + E01 * colv[0][mm + 1] + T10 * colv[1][mm] + E11 * colv[1][mm + 1];
                acc[0][2 * mm + 1] += O00 * colv[0][mm + 1] + T02 * colv[0][mm + 2] + O10 * colv[1][mm + 1] + T12 * colv[1][mm + 2];
                acc[1][2 * mm]     += T20 * colv[1][mm] + E21 * colv[1][mm + 1] + T30 * colv[2][mm] + E31 * colv[2][mm + 1];
                acc[1][2 * mm + 1] += O20 * colv[1][mm + 1] + T22 * colv[1][mm + 2] + O30 * colv[2][mm + 1] + T32 * colv[2][mm + 2];
            }
        }
    }
    const float bias = b4[0];
    const int p_e = strip * 16 + 2 * rp;
    float* ob = out + b * 16384 + p_e * 128 + 4 * cg;
#pragma unroll
    for (int rr = 0; rr < 2; rr++) {
        float4 v;
        v.x = fminf(fmaxf(acc[rr][0] + bias, -1.f), 1.f);
        v.y = fminf(fmaxf(acc[rr][1] + bias, -1.f), 1.f);
        v.z = fminf(fmaxf(acc[rr][2] + bias, -1.f), 1.f);
        v.w = fminf(fmaxf(acc[rr][3] + bias, -1.f), 1.f);
        *(float4*)(ob + rr * 128) = v;
    }
}

extern "C" void kernel_launch(void* const* d_in, const int* in_sizes, int n_in,
                              void* d_out, int out_size, void* d_ws, size_t ws_size,
                              hipStream_t stream) {
    const float* x  = (const float*)d_in[0];
    const float* w1 = (const float*)d_in[1];
    const float* b1 = (const float*)d_in[2];
    const float* w2 = (const float*)d_in[3];
    const float* b2 = (const float*)d_in[4];
    const float* cb = (const float*)d_in[5];
    const float* w3 = (const float*)d_in[6];
    const float* b3 = (const float*)d_in[7];
    const float* w4 = (const float*)d_in[8];
    const float* b4 = (const float*)d_in[9];

    float* ws = (float*)d_ws;
    float* h1 = ws;                   // 8388608 floats [128,16,64,64]
    float* h  = ws + 8388608;         // 4194304 floats [128,32,32,32]
    float* g  = h1;                   // alias: h1 dead after conv2
    float* ccp = ws + 12582912;       // 512
    float* pa  = ws + 12583424;       // 2048 (per-vq-block loss partials)
    float* w4t = ws + 12585472;       // 256

    float* outp = (float*)d_out;      // final: [out 2097152][idx 131072][loss 1]
    // d_out's `out` region doubles as weight-table scratch until kC overwrites it:
    float* w3t = outp;                // 8192 floats (kA write, kB read)
    f32x2* w2d = (f32x2*)(outp + 8192); // 4608 f32x2 (kA write, k_conv2 read)
    float* idx = outp + 2097152;
    float* loss = outp + 2228224;

    kA<<<2050, 256, 0, stream>>>(x, w1, b1, h1, cb, w3, w4, ccp, w3t, w4t, w2d, w2);
    k_conv2<<<2048, 256, 0, stream>>>(h1, w2d, b2, h);
    kB<<<2560, 256, 0, stream>>>(h, w3t, b3, g, cb, ccp, idx, pa);
    kC<<<1025, 256, 0, stream>>>(g, w4t, b4, outp, pa, loss);
}